// Round 4
// baseline (87.480 us; speedup 1.0000x reference)
//
#include <hip/hip_runtime.h>
#include <hip/hip_bf16.h>
#include <cstddef>

// B=8, L=1024, E=1024, H=8, d=128
// out = BandedGaussianAttn(values @ Win^T) @ Wout^T
// Identity used: Att[q,e] = smooth(values)[q + ofs_h(e)] . Win[e,:]
//   (std equal across heads -> smoothing is head-independent; offset becomes
//    a per-output-column-block row shift of the GEMM1 A operand)
// Pipeline: smooth_cvt (fp32->bf16, 13-tap along q, +weight cvt)
//        -> GEMM1 shifted-A (bf16->bf16)  -> GEMM2 (bf16->fp32)

#define BATCH 8
#define SEQL  1024
#define EMB   1024
#define VROWS 1032   // padded rows/batch: r in [0,1032) represents p = r-4 in [-4,1028)
#define RAD   6

typedef unsigned short u16;
typedef __attribute__((ext_vector_type(8))) short s16x8;
typedef __attribute__((ext_vector_type(4))) float f32x4;
typedef __attribute__((ext_vector_type(8))) unsigned short u16x8;

#define GLOAD_LDS16(g, l)                                                     \
    __builtin_amdgcn_global_load_lds(                                         \
        (const __attribute__((address_space(1))) void*)(g),                   \
        (__attribute__((address_space(3))) void*)(l), 16, 0, 0)

__device__ __forceinline__ u16 f2bf(float f) {
    unsigned u = __builtin_bit_cast(unsigned, f);
    u += 0x7FFF + ((u >> 16) & 1);
    return (u16)(u >> 16);
}

__constant__ float c_w[2 * RAD + 1] = {
    6.075882849823286e-09f, 1.4867195147342979e-06f, 1.3383022576488537e-04f,
    4.431848411938008e-03f, 5.399096651318806e-02f,  2.4197072451914337e-01f,
    3.989422804014327e-01f,
    2.4197072451914337e-01f, 5.399096651318806e-02f, 4.431848411938008e-03f,
    1.3383022576488537e-04f, 1.4867195147342979e-06f, 6.075882849823286e-09f
};
__constant__ int c_ofs[8] = { -3, -2, -1, 0, 0, 1, 2, 3 };

// ---------- smooth_cvt: VG[b,r,:] = bf16( sum_j w[j]*values[b,r-4+j,:] ) ----------
// plus fp32->bf16 cvt of Win/Wout.  mask folded into tap skip (masked_fill on v).
__global__ __launch_bounds__(256) void smooth_cvt(
    const float* __restrict__ values, const unsigned char* __restrict__ mask,
    const float* __restrict__ wi, const float* __restrict__ wo,
    u16* __restrict__ VG, u16* __restrict__ wib, u16* __restrict__ wob)
{
    const int i = blockIdx.x * 256 + threadIdx.x;
    const int NVG = BATCH * VROWS * 128;               // 1,056,768 u16x8 chunks
    if (i < NVG) {
        const int e = (i & 127) * 8;
        const int r = (i >> 7) % VROWS;
        const int b = i / (128 * VROWS);
        const int p = r - 4;
        float acc[8] = {};
        #pragma unroll
        for (int j = -RAD; j <= RAD; ++j) {
            const int v = p + j;
            if (v < 0 || v >= SEQL) continue;
            if (mask[b * SEQL + v]) continue;
            const float w = c_w[j + RAD];
            const float* src = values + (size_t)(b * SEQL + v) * EMB + e;
            const float4 x0 = *(const float4*)src;
            const float4 x1 = *(const float4*)(src + 4);
            acc[0] = fmaf(w, x0.x, acc[0]); acc[1] = fmaf(w, x0.y, acc[1]);
            acc[2] = fmaf(w, x0.z, acc[2]); acc[3] = fmaf(w, x0.w, acc[3]);
            acc[4] = fmaf(w, x1.x, acc[4]); acc[5] = fmaf(w, x1.y, acc[5]);
            acc[6] = fmaf(w, x1.z, acc[6]); acc[7] = fmaf(w, x1.w, acc[7]);
        }
        u16x8 o;
        #pragma unroll
        for (int t = 0; t < 8; ++t) o[t] = f2bf(acc[t]);
        *(u16x8*)&VG[(size_t)(b * VROWS + r) * EMB + e] = o;
    } else {
        const int k = i - NVG;                         // 0..262143
        const float* src = (k < 131072) ? wi : wo;
        u16* dst = (k < 131072) ? wib : wob;
        const size_t off = (size_t)(k & 131071) * 8;
        const float4 a = *(const float4*)(src + off);
        const float4 b4 = *(const float4*)(src + off + 4);
        u16x8 o;
        o[0] = f2bf(a.x);  o[1] = f2bf(a.y);  o[2] = f2bf(a.z);  o[3] = f2bf(a.w);
        o[4] = f2bf(b4.x); o[5] = f2bf(b4.y); o[6] = f2bf(b4.z); o[7] = f2bf(b4.w);
        *(u16x8*)(dst + off) = o;
    }
}

// ---------- pipelined bf16 MFMA GEMM: C[M,N] = A[M,K]*B[N,K]^T ----------
// BM=256 BN=128 BK=64, 512 thr / 8 waves (4M x 2N, per-wave 64x64).
// 3-buffer LDS, 2 fine phases per K-tile (m201-style), vmcnt(6) counted,
// T2 XOR-chunk swizzle (both-sides involution), T5 setprio, T1 XCD swizzle.
constexpr int BM = 256, BN = 128, BK = 64;
constexpr int A_EL = BM * BK;            // 16384 elems (32 KB)
constexpr int B_EL = BN * BK;            // 8192 elems (16 KB)
constexpr int BUF_EL = A_EL + B_EL;      // 48 KB per buffer; x3 = 144 KB

template <bool OUT_BF16, bool SHIFTED>
__global__ __launch_bounds__(512, 2) void gemm_nt_pipe(
    const u16* __restrict__ A, const u16* __restrict__ B,
    void* __restrict__ Cout, int M, int N, int K)
{
    __shared__ u16 lds[3 * BUF_EL];

    const int tid  = threadIdx.x;
    const int lane = tid & 63;
    const int wave = tid >> 6;

    // T1: bijective XCD swizzle (gridDim.x % 8 == 0)
    const int nwg = gridDim.x;
    const int bid = blockIdx.x;
    const int swz = (bid & 7) * (nwg >> 3) + (bid >> 3);
    const int ntn = N >> 7;
    const int row0 = (swz / ntn) * BM;
    const int col0 = (swz % ntn) * BN;

    // GEMM1: A row base shifted by per-head offset into padded VG space
    int arow0;
    if (SHIFTED) {
        const int b  = row0 >> 10;            // BM=256 | 1024 -> no batch straddle
        const int q0 = row0 & (SEQL - 1);
        arow0 = b * VROWS + q0 + 4 + c_ofs[col0 >> 7];
    } else {
        arow0 = row0;
    }
    const u16* Ab = A + (size_t)arow0 * K;
    const u16* Bb = B + (size_t)col0 * K;

    const int wm = wave >> 1;    // 0..3 (M quarter)
    const int wn = wave & 1;     // 0..1 (N half)
    const int fr = lane & 15;
    const int fg = lane >> 4;

    const int srow   = tid >> 3;      // 0..63
    const int schunk = tid & 7;       // 16B chunk in 128B row

    f32x4 acc[4][4] = {};
    s16x8 af[4][2], bf0[2][2], bf1[2][2];

    // stage: LDS linear (row,chunk) <- global (row, chunk ^ (row&7))  [T2]
    auto stageA3 = [&](int bsel, int kt) {
        u16* Abuf = lds + bsel * BUF_EL;
        const int k0 = kt << 6;
        #pragma unroll
        for (int c = 0; c < 3; ++c) {
            const int row = c * 64 + srow;
            const int sc  = (schunk ^ (row & 7)) << 3;
            GLOAD_LDS16(Ab + (size_t)row * K + k0 + sc, Abuf + c * 4096 + wave * 512);
        }
    };
    auto stageRest = [&](int bsel, int kt) {
        u16* Abuf = lds + bsel * BUF_EL;
        u16* Bbuf = Abuf + A_EL;
        const int k0 = kt << 6;
        {
            const int row = 192 + srow;
            const int sc  = (schunk ^ (row & 7)) << 3;
            GLOAD_LDS16(Ab + (size_t)row * K + k0 + sc, Abuf + 3 * 4096 + wave * 512);
        }
        #pragma unroll
        for (int c = 0; c < 2; ++c) {
            const int row = c * 64 + srow;
            const int sc  = (schunk ^ (row & 7)) << 3;
            GLOAD_LDS16(Bb + (size_t)row * K + k0 + sc, Bbuf + c * 4096 + wave * 512);
        }
    };

    // phase 0: read A(all m) + B(n0,n1), issue 3 stage loads, MFMA n0..1
    auto phase0 = [&](int tile, bool doStage) {
        const u16* Abuf = lds + (tile % 3) * BUF_EL;
        const u16* Bbuf = Abuf + A_EL;
        #pragma unroll
        for (int m = 0; m < 4; ++m)
            #pragma unroll
            for (int kk = 0; kk < 2; ++kk) {
                const int row = wm * 64 + m * 16 + fr;
                const int ch  = ((kk << 2) + fg) ^ (row & 7);
                af[m][kk] = *(const s16x8*)(Abuf + row * 64 + ch * 8);
            }
        #pragma unroll
        for (int n = 0; n < 2; ++n)
            #pragma unroll
            for (int kk = 0; kk < 2; ++kk) {
                const int row = wn * 64 + n * 16 + fr;
                const int ch  = ((kk << 2) + fg) ^ (row & 7);
                bf0[n][kk] = *(const s16x8*)(Bbuf + row * 64 + ch * 8);
            }
        if (doStage) stageA3((tile + 2) % 3, tile + 2);
        __builtin_amdgcn_s_barrier();
        asm volatile("s_waitcnt lgkmcnt(0)" ::: "memory");
        __builtin_amdgcn_sched_barrier(0);
        __builtin_amdgcn_s_setprio(1);
        #pragma unroll
        for (int m = 0; m < 4; ++m)
            #pragma unroll
            for (int n = 0; n < 2; ++n)
                #pragma unroll
                for (int kk = 0; kk < 2; ++kk)
                    acc[m][n] = __builtin_amdgcn_mfma_f32_16x16x32_bf16(
                        af[m][kk], bf0[n][kk], acc[m][n], 0, 0, 0);
        __builtin_amdgcn_s_setprio(0);
        __builtin_amdgcn_s_barrier();
    };

    // phase 1: read B(n2,n3) (A reused), issue 3 stage loads + vmcnt, MFMA n2..3
    auto phase1 = [&](int tile, int mode /*0: stage+vm6, 1: vm0, 2: none*/) {
        const u16* Abuf = lds + (tile % 3) * BUF_EL;
        const u16* Bbuf = Abuf + A_EL;
        #pragma unroll
        for (int n = 0; n < 2; ++n)
            #pragma unroll
            for (int kk = 0; kk < 2; ++kk) {
                const int row = wn * 64 + (2 + n) * 16 + fr;
                const int ch  = ((kk << 2) + fg) ^ (row & 7);
                bf1[n][kk] = *(const s16x8*)(Bbuf + row * 64 + ch * 8);
            }
        if (mode == 0) {
            stageRest((tile + 2) % 3, tile + 2);
            asm volatile("s_waitcnt vmcnt(6)" ::: "memory");   // tile+1 resident
        } else if (mode == 1) {
            asm volatile("s_waitcnt vmcnt(0)" ::: "memory");   // last tile resident
        }
        __builtin_amdgcn_s_barrier();
        asm volatile("s_waitcnt lgkmcnt(0)" ::: "memory");
        __builtin_amdgcn_sched_barrier(0);
        __builtin_amdgcn_s_setprio(1);
        #pragma unroll
        for (int m = 0; m < 4; ++m)
            #pragma unroll
            for (int n = 0; n < 2; ++n)
                #pragma unroll
                for (int kk = 0; kk < 2; ++kk)
                    acc[m][2 + n] = __builtin_amdgcn_mfma_f32_16x16x32_bf16(
                        af[m][kk], bf1[n][kk], acc[m][2 + n], 0, 0, 0);
        __builtin_amdgcn_s_setprio(0);
        __builtin_amdgcn_s_barrier();
    };

    const int NT = K >> 6;               // 16

    stageA3(0, 0); stageRest(0, 0);
    stageA3(1, 1); stageRest(1, 1);
    asm volatile("s_waitcnt vmcnt(6)" ::: "memory");  // tile 0 resident
    __builtin_amdgcn_s_barrier();

    for (int t = 0; t < NT - 2; ++t) { phase0(t, true); phase1(t, 0); }
    phase0(NT - 2, false); phase1(NT - 2, 1);
    phase0(NT - 1, false); phase1(NT - 1, 2);

    // C/D layout: col = lane&15, row = fg*4 + j
    const int crow0 = row0 + wm * 64 + fg * 4;
    const int ccol0 = col0 + wn * 64 + fr;
    if (OUT_BF16) {
        u16* C = (u16*)Cout;
        #pragma unroll
        for (int m = 0; m < 4; ++m)
            #pragma unroll
            for (int n = 0; n < 4; ++n)
                #pragma unroll
                for (int j = 0; j < 4; ++j)
                    C[(size_t)(crow0 + m * 16 + j) * N + ccol0 + n * 16] =
                        f2bf(acc[m][n][j]);
    } else {
        float* C = (float*)Cout;
        #pragma unroll
        for (int m = 0; m < 4; ++m)
            #pragma unroll
            for (int n = 0; n < 4; ++n)
                #pragma unroll
                for (int j = 0; j < 4; ++j)
                    C[(size_t)(crow0 + m * 16 + j) * N + ccol0 + n * 16] =
                        acc[m][n][j];
    }
}

extern "C" void kernel_launch(void* const* d_in, const int* in_sizes, int n_in,
                              void* d_out, int out_size, void* d_ws, size_t ws_size,
                              hipStream_t stream) {
    const float* values = (const float*)d_in[0];
    // d_in[1] = queries: only its length matters (Lq == L)
    const unsigned char* mask = (const unsigned char*)d_in[2];
    const float* Win  = (const float*)d_in[3];
    const float* Wout = (const float*)d_in[4];
    float* out = (float*)d_out;

    const int M = BATCH * SEQL;   // 8192
    const int N = EMB;            // 1024
    const int K = EMB;            // 1024

    u16* VG    = (u16*)d_ws;                              // 8*1032*1024 (16.9 MB)
    u16* Attb  = VG + (size_t)BATCH * VROWS * EMB;        // 16 MB
    u16* Winb  = Attb + (size_t)M * EMB;                  // 2 MB
    u16* Woutb = Winb + (size_t)EMB * EMB;                // 2 MB (37.9 MB total)

    // 4128 VG blocks + 1024 weight-cvt blocks
    smooth_cvt<<<5152, 256, 0, stream>>>(values, mask, Win, Wout, VG, Winb, Woutb);

    dim3 ggrid((M / BM) * (N / BN));   // 32*8 = 256 WGs
    gemm_nt_pipe<true,  true ><<<ggrid, 512, 0, stream>>>(VG,   Winb,  Attb, M, N, K);
    gemm_nt_pipe<false, false><<<ggrid, 512, 0, stream>>>(Attb, Woutb, out,  M, N, K);
}